// Round 20
// baseline (170.287 us; speedup 1.0000x reference)
//
#include <hip/hip_runtime.h>

#define BB 2
#define TT 2048
#define CC 768
#define HH 12
#define DD 64
#define TBT (BB * TT)   // 4096 rows

typedef __bf16 bfx8 __attribute__((ext_vector_type(8)));
typedef float f32x4 __attribute__((ext_vector_type(4)));
typedef float f32x16 __attribute__((ext_vector_type(16)));

__device__ __forceinline__ unsigned short f2b(float f) {
  unsigned u = __float_as_uint(f);
  return (unsigned short)((u + 0x7FFFu + ((u >> 16) & 1u)) >> 16);
}
__device__ __forceinline__ float b2f(unsigned short u) {
  return __uint_as_float(((unsigned)u) << 16);
}

__device__ __forceinline__ unsigned pack2bf(float lo, float hi) {
  union { __bf16 h[2]; unsigned u; } x;
  x.h[0] = (__bf16)lo; x.h[1] = (__bf16)hi;
  return x.u;   // compiler emits v_cvt_pk_bf16_f32
}

__device__ __forceinline__ void gload_lds16(const void* g, void* l) {
  __builtin_amdgcn_global_load_lds((const __attribute__((address_space(1))) void*)g,
                                   (__attribute__((address_space(3))) void*)l, 16, 0, 0);
}

// fast exact-enough GELU (tanh form): |err| < 4e-4 vs erf form
__device__ __forceinline__ float gelu_fast(float v) {
  float t = v * v;
  float s = fmaf(0.10294663f, t, 2.3021582f);
  float e = __builtin_amdgcn_exp2f(-v * s);
  return v * __builtin_amdgcn_rcpf(1.0f + e);
}

// ---------------- unified prep: x->bf16 convert + all 4 weight transposes (1 launch) ------
__global__ __launch_bounds__(256) void k_prep(const float* __restrict__ x,
                                              unsigned short* __restrict__ xb,
                                              const float* __restrict__ Wqkv,
                                              unsigned short* __restrict__ WqkvT,
                                              const float* __restrict__ Wo,
                                              unsigned short* __restrict__ WoT,
                                              const float* __restrict__ Wf,
                                              unsigned short* __restrict__ WfT,
                                              const float* __restrict__ Wp,
                                              unsigned short* __restrict__ WpT) {
  __shared__ float tile[32][33];
  int bid = blockIdx.x;
  const int tid = threadIdx.x;
  if (bid < 3072) {
    int i = bid * 1024 + tid * 4;
    float4 v = *(const float4*)(x + i);
    ushort4 o;
    o.x = f2b(v.x); o.y = f2b(v.y); o.z = f2b(v.z); o.w = f2b(v.w);
    *(ushort4*)(xb + i) = o;
    return;
  }
  bid -= 3072;
  const float* W; unsigned short* WT; int K, N, bx, by;
  if (bid < 1728)              { W = Wqkv; WT = WqkvT; K = 768;  N = 2304; bx = bid % 72; by = bid / 72; }
  else if (bid < 1728 + 576)   { bid -= 1728; W = Wo; WT = WoT; K = 768;  N = 768;  bx = bid % 24; by = bid / 24; }
  else if (bid < 1728 + 576 + 2304) { bid -= 1728 + 576; W = Wf; WT = WfT; K = 768; N = 3072; bx = bid % 96; by = bid / 96; }
  else                         { bid -= 1728 + 576 + 2304; W = Wp; WT = WpT; K = 3072; N = 768; bx = bid % 24; by = bid / 24; }
  int n0 = bx * 32, k0 = by * 32;
  int j = tid & 31, i0 = tid >> 5;
  for (int i = i0; i < 32; i += 8) tile[i][j] = W[(size_t)(k0 + i) * N + n0 + j];
  __syncthreads();
  for (int i = i0; i < 32; i += 8) WT[(size_t)(n0 + i) * K + k0 + j] = f2b(tile[j][i]);
}

// ---------------- GEMM: C[M,N] = A[M,K] @ B[K,N],  Bt given as [N,K] ----------------
// 2-phase double-buffered staging: stage(k+1) issued BEFORE compute(k).
// MODE 0: out = bf16(acc + bias); V-column blocks (n0 >= 2C) write transposed into vt
// MODE 1: out = bf16(gelu_fast(acc + bias))
// MODE 3: split-K over blockIdx.z (4 quarters): bf16 partial (no bias);
//         z<2 -> outb + z*M*N, z>=2 -> vt + (z-2)*M*N
template<int MODE>
__global__ __launch_bounds__(256) void k_gemm_bt(const unsigned short* __restrict__ A,
                                                 const unsigned short* __restrict__ Bt,
                                                 const float* __restrict__ bias,
                                                 unsigned short* __restrict__ outb,
                                                 unsigned short* __restrict__ vt,
                                                 int M, int N, int K) {
  __shared__ __align__(16) unsigned short SMEM[4][128 * 64];   // A[2] + B[2], 64KB
  const int tid = threadIdx.x;
  const int l = tid & 63, w = tid >> 6;
  const int wr = w >> 1, wc = w & 1;
  const int lr = l & 15, g = l >> 4;

  const int gx = gridDim.x, nwg = gx * gridDim.y;
  const int orig = blockIdx.x + gx * blockIdx.y;
  const int q8 = nwg >> 3;
  const int swz = (orig & 7) * q8 + (orig >> 3);
  const int m0 = (swz / gx) * 128, n0 = (swz % gx) * 128;

  int kbeg = 0, kend = K;
  if (MODE == 3) { int K4 = K >> 2; kbeg = blockIdx.z * K4; kend = kbeg + K4; }

  f32x4 acc[4][4] = {};

  auto stage = [&](int kt, int buf) {
#pragma unroll
    for (int i = 0; i < 4; ++i) {
      int s = tid + i * 256;           // 16B slot index, 0..1023
      int row = s >> 3;
      int q = (s & 7) ^ (row & 7);     // inverse-swizzled global source (linear LDS dest)
      gload_lds16(A + (size_t)(m0 + row) * K + kt + q * 8, &SMEM[buf][s * 8]);
      gload_lds16(Bt + (size_t)(n0 + row) * K + kt + q * 8, &SMEM[2 + buf][s * 8]);
    }
  };

  stage(kbeg, 0);
  __syncthreads();

  int cur = 0;
  for (int kt = kbeg; kt < kend; kt += 64) {
    if (kt + 64 < kend) stage(kt + 64, cur ^ 1);   // prefetch overlaps compute below
    const unsigned short* As = &SMEM[cur][0];
    const unsigned short* Bs = &SMEM[2 + cur][0];
#pragma unroll
    for (int kk = 0; kk < 2; ++kk) {
      bfx8 af[4], bfr[4];
#pragma unroll
      for (int m = 0; m < 4; ++m) {
        int row = wr * 64 + m * 16 + lr;
        int quad = (kk * 4 + g) ^ (row & 7);
        af[m] = *(const bfx8*)(&As[row * 64 + quad * 8]);
      }
#pragma unroll
      for (int n = 0; n < 4; ++n) {
        int row = wc * 64 + n * 16 + lr;
        int quad = (kk * 4 + g) ^ (row & 7);
        bfr[n] = *(const bfx8*)(&Bs[row * 64 + quad * 8]);
      }
#pragma unroll
      for (int m = 0; m < 4; ++m)
#pragma unroll
        for (int n = 0; n < 4; ++n)
          acc[m][n] = __builtin_amdgcn_mfma_f32_16x16x32_bf16(af[m], bfr[n], acc[m][n], 0, 0, 0);
    }
    __syncthreads();   // drains prefetch (vmcnt) + all waves done with buf[cur]
    cur ^= 1;
  }

  if (MODE == 0 && n0 >= 2 * CC) {
    // ---- fused V transpose: tile -> LDS (XOR-swizzled) -> coalesced vt write ----
    unsigned short* T = &SMEM[0][0];   // 32KB, all waves past final barrier
#pragma unroll
    for (int m = 0; m < 4; ++m)
#pragma unroll
      for (int n = 0; n < 4; ++n) {
        int tcol = wc * 64 + n * 16 + lr;
        float bv = bias[n0 + tcol];
#pragma unroll
        for (int r = 0; r < 4; ++r) {
          int trow = wr * 64 + m * 16 + g * 4 + r;
          T[tcol * 128 + (trow ^ ((tcol & 15) << 3))] = f2b(acc[m][n][r] + bv);
        }
      }
    __syncthreads();
    int tcol = tid >> 1, half = tid & 1;
    int gcol = n0 - 2 * CC + tcol;        // 0..767
    int hh = gcol >> 6, dd = gcol & 63;
    int bloc = m0 >> 11;
    int tb = m0 & 2047;
    unsigned short* dstrow = vt + ((size_t)(bloc * HH + hh) * DD + dd) * TT + tb;
#pragma unroll
    for (int c = 0; c < 8; ++c) {
      int tbase = half * 64 + c * 8;
      bfx8 val = *(const bfx8*)(&T[tcol * 128 + (tbase ^ ((tcol & 15) << 3))]);
      *(bfx8*)(dstrow + tbase) = val;
    }
    return;
  }

  unsigned short* dstb;
  if (MODE == 3) {
    const size_t S = (size_t)M * N;
    dstb = (blockIdx.z < 2) ? (outb + (size_t)blockIdx.z * S)
                            : (vt + (size_t)(blockIdx.z - 2) * S);
  } else {
    dstb = outb;
  }
#pragma unroll
  for (int m = 0; m < 4; ++m) {
#pragma unroll
    for (int n = 0; n < 4; ++n) {
      int col = n0 + wc * 64 + n * 16 + lr;
      float bv = (MODE == 3) ? 0.f : bias[col];
#pragma unroll
      for (int r = 0; r < 4; ++r) {
        int row = m0 + wr * 64 + m * 16 + g * 4 + r;
        float v = acc[m][n][r] + bv;
        if (MODE == 1) v = gelu_fast(v);
        dstb[(size_t)row * N + col] = f2b(v);
      }
    }
  }
}

// ---------------- causal flash attention pass 1: 8 waves / 256 q-rows per block -----------
#define MFIX 8.0f
__device__ const unsigned char CBX8[20]  = {0,1, 2,2, 3,3, 4,4,4, 5,5,5, 6,6,6,6, 7,7,7,7};
__device__ const unsigned char CSUB8[20] = {0,0, 0,1, 0,1, 0,1,2, 0,1,2, 0,1,2,3, 0,1,2,3};
__global__ __launch_bounds__(512) void k_attn(const unsigned short* __restrict__ qkv,
                                              const unsigned short* __restrict__ VT,
                                              unsigned short* __restrict__ aout,
                                              unsigned short* __restrict__ opart,
                                              float* __restrict__ lbuf) {
  __shared__ __align__(16) unsigned short Ks[2][2][64 * 64];   // [dbuf][k-half]
  __shared__ __align__(16) unsigned short Vs[2][2][64 * 64];
  const int tid = threadIdx.x;
  const int l = tid & 63, w = tid >> 6;        // w in 0..7
  const int ql = l & 31, hi = l >> 5;

  // XCD-grouping decode: bijective [0,480) -> (cid in [0,20), bh in [0,24))
  const int id = blockIdx.x;
  const int c8 = id & 7;
  const int r8 = id >> 3;                      // 0..59
  const int cid = r8 % 20;
  const int bh = (r8 / 20) * 8 + c8;
  const int b = bh / HH, h = bh % HH;

  const int bx = CBX8[cid];
  const int sub = CSUB8[cid];
  const int nt = 4 * bx + 4;
  const int nchunks = (nt + 7) >> 3;
  const int t0i = sub * 8;
  const int tcount = min(8, nt - t0i);   // even, >= 4
  const int nIter = tcount >> 1;

  const int qw = bx * 256 + w * 32;    // this wave's 32 q-rows
  const int qrow = qw + ql;

  const unsigned short* Kbase = qkv + (size_t)(b * TT) * (3 * CC) + CC + h * DD;
  const unsigned short* Vbase = VT + (size_t)bh * DD * TT;

  // Q as B-operand frags, pre-scaled to log2 domain
  bfx8 qf[4];
  {
    const unsigned short* qp = qkv + (size_t)(b * TT + qrow) * (3 * CC) + h * DD;
    const float SC = 0.125f * 1.44269504088896340736f;
#pragma unroll
    for (int c = 0; c < 4; ++c) {
      bfx8 rw = *(const bfx8*)(qp + c * 16 + hi * 8);
#pragma unroll
      for (int j = 0; j < 8; ++j) qf[c][j] = (__bf16)((float)rw[j] * SC);
    }
  }

  f32x16 o0 = {}, o1 = {};
  float l_run = 0.f;     // per-half partial; cross-half combined once in epilogue

  // stage one 128-k step (two 64-wide sub-tiles): 512 threads -> 1 slot each per matrix/half
  auto stage = [&](int it, int bufi) {
    const int t64 = t0i + it * 2;
#pragma unroll
    for (int half = 0; half < 2; ++half) {
      const int k0 = (t64 + half) * 64;
      int row = tid >> 3;
      int q = (tid & 7) ^ (row & 7);
      gload_lds16(Kbase + (size_t)(k0 + row) * (3 * CC) + q * 8, &Ks[bufi][half][tid * 8]);
      gload_lds16(Vbase + (size_t)row * TT + k0 + q * 8, &Vs[bufi][half][tid * 8]);
    }
  };

  stage(0, 0);
  __syncthreads();

  int cur = 0;
  for (int it = 0; it < nIter; ++it) {
    if (it + 1 < nIter) stage(it + 1, cur ^ 1);   // prefetch overlaps both halves below

#pragma unroll
    for (int h2 = 0; h2 < 2; ++h2) {
      const int t = t0i + it * 2 + h2;
      const int k0 = t * 64;
      if (k0 <= qw + 31) {   // wave-uniform: skip fully-masked sub-tiles
        f32x16 sa[2];
        __builtin_amdgcn_s_setprio(1);
#pragma unroll
        for (int kh = 0; kh < 2; ++kh) {
          f32x16 acc = {};
          int row = kh * 32 + ql;
          int rx = row & 7;
#pragma unroll
          for (int c = 0; c < 4; ++c) {
            int quad = (c * 2 + hi) ^ rx;
            bfx8 kf = *(const bfx8*)(&Ks[cur][h2][row * 64 + quad * 8]);
            acc = __builtin_amdgcn_mfma_f32_32x32x16_bf16(kf, qf[c], acc, 0, 0, 0);
          }
          sa[kh] = acc;
        }
        __builtin_amdgcn_s_setprio(0);

        if (k0 + 63 > qw) {   // diagonal-region mask
#pragma unroll
          for (int kh = 0; kh < 2; ++kh)
#pragma unroll
            for (int r = 0; r < 16; ++r) {
              int kk = k0 + kh * 32 + (r & 3) + 8 * (r >> 2) + 4 * hi;
              if (kk > qrow) sa[kh][r] = -1e30f;
            }
        }

        // ---- p = exp2(s - MFIX) directly; 4 independent sum chains ----
        float rs0 = 0.f, rs1 = 0.f, rs2 = 0.f, rs3 = 0.f;
        unsigned pk[2][8];
#pragma unroll
        for (int kh = 0; kh < 2; ++kh)
#pragma unroll
          for (int i = 0; i < 8; ++i) {
            float p0 = __builtin_amdgcn_exp2f(sa[kh][2 * i] - MFIX);
            float p1 = __builtin_amdgcn_exp2f(sa[kh][2 * i + 1] - MFIX);
            float ps = p0 + p1;
            if ((i & 3) == 0) rs0 += ps;
            else if ((i & 3) == 1) rs1 += ps;
            else if ((i & 3) == 2) rs2 += ps;
            else rs3 += ps;
            pk[kh][i] = pack2bf(p0, p1);
          }
        l_run += (rs0 + rs1) + (rs2 + rs3);

        // ---- in-register P^T -> B-frags via permlane32_swap ----
        bfx8 pf[4];
#pragma unroll
        for (int kh = 0; kh < 2; ++kh)
#pragma unroll
          for (int c = 0; c < 2; ++c) {
            unsigned a0 = pk[kh][c * 4 + 0], a1 = pk[kh][c * 4 + 1];
            unsigned b0 = pk[kh][c * 4 + 2], b1 = pk[kh][c * 4 + 3];
            asm volatile("v_permlane32_swap_b32 %0, %1" : "+v"(a0), "+v"(b0));
            asm volatile("v_permlane32_swap_b32 %0, %1" : "+v"(a1), "+v"(b1));
            union { unsigned u[4]; bfx8 v; } cvt;
            cvt.u[0] = a0; cvt.u[1] = a1; cvt.u[2] = b0; cvt.u[3] = b1;
            pf[kh * 2 + c] = cvt.v;
          }

        __builtin_amdgcn_s_setprio(1);
#pragma unroll
        for (int kc = 0; kc < 4; ++kc) {
          {
            int row = ql;
            bfx8 vf = *(const bfx8*)(&Vs[cur][h2][row * 64 + (((kc * 2 + hi) ^ (row & 7)) * 8)]);
            o0 = __builtin_amdgcn_mfma_f32_32x32x16_bf16(vf, pf[kc], o0, 0, 0, 0);
          }
          {
            int row = 32 + ql;
            bfx8 vf = *(const bfx8*)(&Vs[cur][h2][row * 64 + (((kc * 2 + hi) ^ (row & 7)) * 8)]);
            o1 = __builtin_amdgcn_mfma_f32_32x32x16_bf16(vf, pf[kc], o1, 0, 0, 0);
          }
        }
        __builtin_amdgcn_s_setprio(0);
      }
    }

    __syncthreads();   // one barrier per 128-k step
    cur ^= 1;
  }

  // combine cross-half l once (sums commute over tiles)
  l_run += __shfl_xor(l_run, 32);

  if (nchunks == 1) {
    float inv = 1.0f / l_run;
    unsigned short* orow = aout + (size_t)(b * TT + qrow) * CC + h * DD;
#pragma unroll
    for (int dh = 0; dh < 2; ++dh) {
      const f32x16& oo = dh ? o1 : o0;
#pragma unroll
      for (int qd = 0; qd < 4; ++qd) {
        ushort4 v;
        v.x = f2b(oo[qd * 4 + 0] * inv);
        v.y = f2b(oo[qd * 4 + 1] * inv);
        v.z = f2b(oo[qd * 4 + 2] * inv);
        v.w = f2b(oo[qd * 4 + 3] * inv);
        *(ushort4*)(orow + dh * 32 + 8 * qd + 4 * hi) = v;
      }
    }
  } else {
    unsigned short* orow = opart + (size_t)sub * TBT * CC + (size_t)(b * TT + qrow) * CC + h * DD;
#pragma unroll
    for (int dh = 0; dh < 2; ++dh) {
      const f32x16& oo = dh ? o1 : o0;
#pragma unroll
      for (int qd = 0; qd < 4; ++qd) {
        ushort4 v;
        v.x = f2b(oo[qd * 4 + 0]);
        v.y = f2b(oo[qd * 4 + 1]);
        v.z = f2b(oo[qd * 4 + 2]);
        v.w = f2b(oo[qd * 4 + 3]);
        *(ushort4*)(orow + dh * 32 + 8 * qd + 4 * hi) = v;
      }
    }
    if (hi == 0) lbuf[((size_t)sub * (BB * HH) + bh) * TT + qrow] = l_run;
  }
}

// ---------------- attention combine: plain sum of partials (shared fixed m) --------------
// Grid covers ONLY the multi-chunk region t in [512, 2048) per batch.
__global__ __launch_bounds__(256) void k_attn_combine(const unsigned short* __restrict__ opart,
                                                      const float* __restrict__ lbuf,
                                                      unsigned short* __restrict__ aout) {
  int lin = (blockIdx.x * 256 + threadIdx.x) * 4;   // over BB x 1536 x CC elems
  int b = lin / (1536 * CC);
  int rem = lin - b * (1536 * CC);
  int t = 512 + rem / CC;
  int c = rem % CC;
  int idx = (b * TT + t) * CC + c;
  int bx8 = t >> 8;
  int cnt = (4 * bx8 + 11) >> 3;               // 2..4 in this region
  int h = c >> 6;
  int bh = b * HH + h;

  float lsum = 0.f;
#pragma unroll
  for (int s = 0; s < 4; ++s)
    if (s < cnt) lsum += lbuf[((size_t)s * (BB * HH) + bh) * TT + t];
  float linv = 1.0f / lsum;

  float a0 = 0.f, a1 = 0.f, a2 = 0.f, a3 = 0.f;
#pragma unroll
  for (int s = 0; s < 4; ++s)
    if (s < cnt) {
      ushort4 v = *(const ushort4*)(opart + (size_t)s * TBT * CC + idx);
      a0 += b2f(v.x);
      a1 += b2f(v.y);
      a2 += b2f(v.z);
      a3 += b2f(v.w);
    }
  ushort4 o;
  o.x = f2b(a0 * linv);
  o.y = f2b(a1 * linv);
  o.z = f2b(a2 * linv);
  o.w = f2b(a3 * linv);
  *(ushort4*)(aout + idx) = o;
}

// ---------------- LayerNorm+combine: v = sum of 4 bf16 partials + resid + bias, then LN --
template<int OUTF32, int RESB16>
__global__ __launch_bounds__(256) void k_layernorm_c(const unsigned short* __restrict__ in0,
                                                     const unsigned short* __restrict__ in1,
                                                     const unsigned short* __restrict__ in2,
                                                     const unsigned short* __restrict__ in3,
                                                     const float* __restrict__ residf,
                                                     const unsigned short* __restrict__ residb,
                                                     const float* __restrict__ biasv,
                                                     const float* __restrict__ gw,
                                                     const float* __restrict__ bw,
                                                     float* __restrict__ outf,
                                                     unsigned short* __restrict__ outb) {
  __shared__ float red[8];
  const int row = blockIdx.x;
  const int tid = threadIdx.x;
  float v[3];
  float s = 0.f;
#pragma unroll
  for (int j = 0; j < 3; ++j) {
    int c = tid + j * 256;
    size_t idx = (size_t)row * CC + c;
    float rv = RESB16 ? b2f(residb[idx]) : residf[idx];
    v[j] = (b2f(in0[idx]) + b2f(in1[idx])) + (b2f(in2[idx]) + b2f(in3[idx])) + rv + biasv[c];
    s += v[j];
  }
#pragma unroll
  for (int off = 32; off; off >>= 1) s += __shfl_xor(s, off);
  if ((tid & 63) == 0) red[tid >> 6] = s;
  __syncthreads();
  s = red[0] + red[1] + red[2] + red[3];
  float mu = s * (1.0f / CC);
  float qs = 0.f;
#pragma unroll
  for (int j = 0; j < 3; ++j) { float d = v[j] - mu; qs += d * d; }
#pragma unroll
  for (int off = 32; off; off >>= 1) qs += __shfl_xor(qs, off);
  if ((tid & 63) == 0) red[4 + (tid >> 6)] = qs;
  __syncthreads();
  qs = red[4] + red[5] + red[6] + red[7];
  float rstd = rsqrtf(qs * (1.0f / CC) + 1e-5f);
#pragma unroll
  for (int j = 0; j < 3; ++j) {
    int c = tid + j * 256;
    float y = (v[j] - mu) * rstd * gw[c] + bw[c];
    if (OUTF32) outf[(size_t)row * CC + c] = y;
    else        outb[(size_t)row * CC + c] = f2b(y);
  }
}

extern "C" void kernel_launch(void* const* d_in, const int* in_sizes, int n_in,
                              void* d_out, int out_size, void* d_ws, size_t ws_size,
                              hipStream_t stream) {
  (void)in_sizes; (void)n_in; (void)out_size; (void)ws_size;
  const float* x    = (const float*)d_in[0];
  const float* Wqkv = (const float*)d_in[1];
  const float* bqkv = (const float*)d_in[2];
  const float* Wo   = (const float*)d_in[3];
  const float* bo   = (const float*)d_in[4];
  const float* ln1g = (const float*)d_in[5];
  const float* ln1b = (const float*)d_in[6];
  const float* Wf   = (const float*)d_in[7];
  const float* bf_  = (const float*)d_in[8];
  const float* Wp   = (const float*)d_in[9];
  const float* bp   = (const float*)d_in[10];
  const float* ln2g = (const float*)d_in[11];
  const float* ln2b = (const float*)d_in[12];

  char* ws = (char*)d_ws;
  size_t off = 0;
  auto alloc = [&](size_t bytes) {
    void* p = ws + off;
    off += (bytes + 255) & ~(size_t)255;
    return p;
  };
  unsigned short* xb    = (unsigned short*)alloc((size_t)TBT * CC * 2);
  unsigned short* WqkvT = (unsigned short*)alloc((size_t)3 * CC * CC * 2);
  unsigned short* WoT   = (unsigned short*)alloc((size_t)CC * CC * 2);
  unsigned short* WfT   = (unsigned short*)alloc((size_t)4 * CC * CC * 2);
  unsigned short* WpT   = (unsigned short*)alloc((size_t)4 * CC * CC * 2);
  unsigned short* qkvb  = (unsigned short*)alloc((size_t)TBT * 3 * CC * 2);
  unsigned short* VTb   = (unsigned short*)alloc((size_t)TBT * CC * 2);
  float*          hbuf  = (float*)alloc((size_t)TBT * CC * 4);
  unsigned short* hlnb  = (unsigned short*)alloc((size_t)TBT * CC * 2);
  unsigned short* gbuf  = (unsigned short*)alloc((size_t)TBT * 4 * CC * 2);

  const size_t S = (size_t)TBT * CC;

  // aliases (lifetime-disjoint):
  unsigned short* aout  = xb;                               // attn final out (xb dead after QKV GEMM)
  unsigned short* opart = gbuf;                             // attn O-partials, 4 x 6.3MB bf16
  float*          lvals = (float*)hbuf;                     // attn l sums (hbuf free here)
  unsigned short* woP01 = gbuf;                             // Wo split-K4 partials z=0,1 (opart dead)
  unsigned short* woP23 = gbuf + 2 * S;                     // z=2,3
  unsigned short* fpP01 = (unsigned short*)hbuf;            // FFN2 split-K4 partials z=0,1 (lvals dead)
  unsigned short* fpP23 = qkvb;                             // z=2,3 (qkvb dead after attention)

  // prep: x->bf16 + all 4 weight transposes (single launch)
  k_prep<<<9984, 256, 0, stream>>>(x, xb, Wqkv, WqkvT, Wo, WoT, Wf, WfT, Wp, WpT);

  // qkv = x @ Wqkv + bqkv -> bf16 [4096, 2304]; V columns transposed straight into VTb
  k_gemm_bt<0><<<dim3(3 * CC / 128, TBT / 128), 256, 0, stream>>>(
      xb, WqkvT, bqkv, qkvb, VTb, TBT, 3 * CC, CC);
  // attention pass 1 (8-wave blocks, 256 q-rows, KVBLK=128, XCD-grouped) -> aout + opart/l
  k_attn<<<480, 512, 0, stream>>>(qkvb, VTb, aout, opart, lvals);
  // combine multi-chunk rows (plain sum, t>=512 region only) -> aout bf16
  k_attn_combine<<<(BB * 1536 * CC) / 1024, 256, 0, stream>>>(opart, lvals, aout);
  // attn @ Wo (split-K=4) -> woP01/woP23 bf16 partials
  k_gemm_bt<3><<<dim3(CC / 128, TBT / 128, 4), 256, 0, stream>>>(
      aout, WoT, nullptr, woP01, woP23, TBT, CC, CC);
  // LN1( sum woP + x + bo ) -> hlnb (bf16)
  k_layernorm_c<0, 0><<<TBT, 256, 0, stream>>>(woP01, woP01 + S, woP23, woP23 + S,
                                               x, nullptr, bo, ln1g, ln1b, nullptr, hlnb);
  // g = gelu(hlnb @ Wf + bf) -> bf16 [4096, 3072]
  k_gemm_bt<1><<<dim3(4 * CC / 128, TBT / 128), 256, 0, stream>>>(
      hlnb, WfT, bf_, gbuf, nullptr, TBT, 4 * CC, CC);
  // g @ Wp (split-K=4) -> fpP01/fpP23 bf16 partials
  k_gemm_bt<3><<<dim3(CC / 128, TBT / 128, 4), 256, 0, stream>>>(
      gbuf, WpT, nullptr, fpP01, fpP23, TBT, CC, 4 * CC);
  // LN2( sum fpP + hlnb + bp ) -> d_out (f32)
  k_layernorm_c<1, 1><<<TBT, 256, 0, stream>>>(fpP01, fpP01 + S, fpP23, fpP23 + S,
                                               nullptr, hlnb, bp, ln2g, ln2b,
                                               (float*)d_out, nullptr);
}

// Round 21
// 168.728 us; speedup vs baseline: 1.0092x; 1.0092x over previous
//
#include <hip/hip_runtime.h>

#define BB 2
#define TT 2048
#define CC 768
#define HH 12
#define DD 64
#define TBT (BB * TT)   // 4096 rows

typedef __bf16 bfx8 __attribute__((ext_vector_type(8)));
typedef float f32x4 __attribute__((ext_vector_type(4)));
typedef float f32x16 __attribute__((ext_vector_type(16)));

__device__ __forceinline__ unsigned short f2b(float f) {
  unsigned u = __float_as_uint(f);
  return (unsigned short)((u + 0x7FFFu + ((u >> 16) & 1u)) >> 16);
}
__device__ __forceinline__ float b2f(unsigned short u) {
  return __uint_as_float(((unsigned)u) << 16);
}

__device__ __forceinline__ unsigned pack2bf(float lo, float hi) {
  union { __bf16 h[2]; unsigned u; } x;
  x.h[0] = (__bf16)lo; x.h[1] = (__bf16)hi;
  return x.u;   // compiler emits v_cvt_pk_bf16_f32
}

__device__ __forceinline__ void gload_lds16(const void* g, void* l) {
  __builtin_amdgcn_global_load_lds((const __attribute__((address_space(1))) void*)g,
                                   (__attribute__((address_space(3))) void*)l, 16, 0, 0);
}

// fast exact-enough GELU (tanh form): |err| < 4e-4 vs erf form
__device__ __forceinline__ float gelu_fast(float v) {
  float t = v * v;
  float s = fmaf(0.10294663f, t, 2.3021582f);
  float e = __builtin_amdgcn_exp2f(-v * s);
  return v * __builtin_amdgcn_rcpf(1.0f + e);
}

// ---------------- unified prep: x->bf16 convert + all 4 weight transposes (1 launch) ------
__global__ __launch_bounds__(256) void k_prep(const float* __restrict__ x,
                                              unsigned short* __restrict__ xb,
                                              const float* __restrict__ Wqkv,
                                              unsigned short* __restrict__ WqkvT,
                                              const float* __restrict__ Wo,
                                              unsigned short* __restrict__ WoT,
                                              const float* __restrict__ Wf,
                                              unsigned short* __restrict__ WfT,
                                              const float* __restrict__ Wp,
                                              unsigned short* __restrict__ WpT) {
  __shared__ float tile[32][33];
  int bid = blockIdx.x;
  const int tid = threadIdx.x;
  if (bid < 3072) {
    int i = bid * 1024 + tid * 4;
    float4 v = *(const float4*)(x + i);
    ushort4 o;
    o.x = f2b(v.x); o.y = f2b(v.y); o.z = f2b(v.z); o.w = f2b(v.w);
    *(ushort4*)(xb + i) = o;
    return;
  }
  bid -= 3072;
  const float* W; unsigned short* WT; int K, N, bx, by;
  if (bid < 1728)              { W = Wqkv; WT = WqkvT; K = 768;  N = 2304; bx = bid % 72; by = bid / 72; }
  else if (bid < 1728 + 576)   { bid -= 1728; W = Wo; WT = WoT; K = 768;  N = 768;  bx = bid % 24; by = bid / 24; }
  else if (bid < 1728 + 576 + 2304) { bid -= 1728 + 576; W = Wf; WT = WfT; K = 768; N = 3072; bx = bid % 96; by = bid / 96; }
  else                         { bid -= 1728 + 576 + 2304; W = Wp; WT = WpT; K = 3072; N = 768; bx = bid % 24; by = bid / 24; }
  int n0 = bx * 32, k0 = by * 32;
  int j = tid & 31, i0 = tid >> 5;
  for (int i = i0; i < 32; i += 8) tile[i][j] = W[(size_t)(k0 + i) * N + n0 + j];
  __syncthreads();
  for (int i = i0; i < 32; i += 8) WT[(size_t)(n0 + i) * K + k0 + j] = f2b(tile[j][i]);
}

// ---------------- GEMM: C[M,N] = A[M,K] @ B[K,N],  Bt given as [N,K] ----------------
// 2-phase double-buffered staging: stage(k+1) issued BEFORE compute(k).
// MODE 0: out = bf16(acc + bias); V-column blocks (n0 >= 2C) write transposed into vt
// MODE 1: out = bf16(gelu_fast(acc + bias))
// MODE 3: split-K over blockIdx.z (gridDim.z slices): bf16 partial (no bias);
//         z<2 -> outb + z*M*N, z>=2 -> vt + (z-2)*M*N
template<int MODE>
__global__ __launch_bounds__(256) void k_gemm_bt(const unsigned short* __restrict__ A,
                                                 const unsigned short* __restrict__ Bt,
                                                 const float* __restrict__ bias,
                                                 unsigned short* __restrict__ outb,
                                                 unsigned short* __restrict__ vt,
                                                 int M, int N, int K) {
  __shared__ __align__(16) unsigned short SMEM[4][128 * 64];   // A[2] + B[2], 64KB
  const int tid = threadIdx.x;
  const int l = tid & 63, w = tid >> 6;
  const int wr = w >> 1, wc = w & 1;
  const int lr = l & 15, g = l >> 4;

  const int gx = gridDim.x, nwg = gx * gridDim.y;
  const int orig = blockIdx.x + gx * blockIdx.y;
  const int q8 = nwg >> 3;
  const int swz = (orig & 7) * q8 + (orig >> 3);
  const int m0 = (swz / gx) * 128, n0 = (swz % gx) * 128;

  int kbeg = 0, kend = K;
  if (MODE == 3) { int Kz = K / (int)gridDim.z; kbeg = blockIdx.z * Kz; kend = kbeg + Kz; }

  f32x4 acc[4][4] = {};

  auto stage = [&](int kt, int buf) {
#pragma unroll
    for (int i = 0; i < 4; ++i) {
      int s = tid + i * 256;           // 16B slot index, 0..1023
      int row = s >> 3;
      int q = (s & 7) ^ (row & 7);     // inverse-swizzled global source (linear LDS dest)
      gload_lds16(A + (size_t)(m0 + row) * K + kt + q * 8, &SMEM[buf][s * 8]);
      gload_lds16(Bt + (size_t)(n0 + row) * K + kt + q * 8, &SMEM[2 + buf][s * 8]);
    }
  };

  stage(kbeg, 0);
  __syncthreads();

  int cur = 0;
  for (int kt = kbeg; kt < kend; kt += 64) {
    if (kt + 64 < kend) stage(kt + 64, cur ^ 1);   // prefetch overlaps compute below
    const unsigned short* As = &SMEM[cur][0];
    const unsigned short* Bs = &SMEM[2 + cur][0];
#pragma unroll
    for (int kk = 0; kk < 2; ++kk) {
      bfx8 af[4], bfr[4];
#pragma unroll
      for (int m = 0; m < 4; ++m) {
        int row = wr * 64 + m * 16 + lr;
        int quad = (kk * 4 + g) ^ (row & 7);
        af[m] = *(const bfx8*)(&As[row * 64 + quad * 8]);
      }
#pragma unroll
      for (int n = 0; n < 4; ++n) {
        int row = wc * 64 + n * 16 + lr;
        int quad = (kk * 4 + g) ^ (row & 7);
        bfr[n] = *(const bfx8*)(&Bs[row * 64 + quad * 8]);
      }
#pragma unroll
      for (int m = 0; m < 4; ++m)
#pragma unroll
        for (int n = 0; n < 4; ++n)
          acc[m][n] = __builtin_amdgcn_mfma_f32_16x16x32_bf16(af[m], bfr[n], acc[m][n], 0, 0, 0);
    }
    __syncthreads();   // drains prefetch (vmcnt) + all waves done with buf[cur]
    cur ^= 1;
  }

  if (MODE == 0 && n0 >= 2 * CC) {
    // ---- fused V transpose: tile -> LDS (XOR-swizzled) -> coalesced vt write ----
    unsigned short* T = &SMEM[0][0];   // 32KB, all waves past final barrier
#pragma unroll
    for (int m = 0; m < 4; ++m)
#pragma unroll
      for (int n = 0; n < 4; ++n) {
        int tcol = wc * 64 + n * 16 + lr;
        float bv = bias[n0 + tcol];
#pragma unroll
        for (int r = 0; r < 4; ++r) {
          int trow = wr * 64 + m * 16 + g * 4 + r;
          T[tcol * 128 + (trow ^ ((tcol & 15) << 3))] = f2b(acc[m][n][r] + bv);
        }
      }
    __syncthreads();
    int tcol = tid >> 1, half = tid & 1;
    int gcol = n0 - 2 * CC + tcol;        // 0..767
    int hh = gcol >> 6, dd = gcol & 63;
    int bloc = m0 >> 11;
    int tb = m0 & 2047;
    unsigned short* dstrow = vt + ((size_t)(bloc * HH + hh) * DD + dd) * TT + tb;
#pragma unroll
    for (int c = 0; c < 8; ++c) {
      int tbase = half * 64 + c * 8;
      bfx8 val = *(const bfx8*)(&T[tcol * 128 + (tbase ^ ((tcol & 15) << 3))]);
      *(bfx8*)(dstrow + tbase) = val;
    }
    return;
  }

  unsigned short* dstb;
  if (MODE == 3) {
    const size_t S = (size_t)M * N;
    dstb = (blockIdx.z < 2) ? (outb + (size_t)blockIdx.z * S)
                            : (vt + (size_t)(blockIdx.z - 2) * S);
  } else {
    dstb = outb;
  }
#pragma unroll
  for (int m = 0; m < 4; ++m) {
#pragma unroll
    for (int n = 0; n < 4; ++n) {
      int col = n0 + wc * 64 + n * 16 + lr;
      float bv = (MODE == 3) ? 0.f : bias[col];
#pragma unroll
      for (int r = 0; r < 4; ++r) {
        int row = m0 + wr * 64 + m * 16 + g * 4 + r;
        float v = acc[m][n][r] + bv;
        if (MODE == 1) v = gelu_fast(v);
        dstb[(size_t)row * N + col] = f2b(v);
      }
    }
  }
}

// ---------------- causal flash attention pass 1: 8 waves / 256 q-rows per block -----------
#define MFIX 8.0f
__device__ const unsigned char CBX8[20]  = {0,1, 2,2, 3,3, 4,4,4, 5,5,5, 6,6,6,6, 7,7,7,7};
__device__ const unsigned char CSUB8[20] = {0,0, 0,1, 0,1, 0,1,2, 0,1,2, 0,1,2,3, 0,1,2,3};
__global__ __launch_bounds__(512) void k_attn(const unsigned short* __restrict__ qkv,
                                              const unsigned short* __restrict__ VT,
                                              unsigned short* __restrict__ aout,
                                              unsigned short* __restrict__ opart,
                                              float* __restrict__ lbuf) {
  __shared__ __align__(16) unsigned short Ks[2][2][64 * 64];   // [dbuf][k-half]
  __shared__ __align__(16) unsigned short Vs[2][2][64 * 64];
  const int tid = threadIdx.x;
  const int l = tid & 63, w = tid >> 6;        // w in 0..7
  const int ql = l & 31, hi = l >> 5;

  // XCD-grouping decode: bijective [0,480) -> (cid in [0,20), bh in [0,24))
  const int id = blockIdx.x;
  const int c8 = id & 7;
  const int r8 = id >> 3;                      // 0..59
  const int cid = r8 % 20;
  const int bh = (r8 / 20) * 8 + c8;
  const int b = bh / HH, h = bh % HH;

  const int bx = CBX8[cid];
  const int sub = CSUB8[cid];
  const int nt = 4 * bx + 4;
  const int nchunks = (nt + 7) >> 3;
  const int t0i = sub * 8;
  const int tcount = min(8, nt - t0i);   // even, >= 4
  const int nIter = tcount >> 1;

  const int qw = bx * 256 + w * 32;    // this wave's 32 q-rows
  const int qrow = qw + ql;

  const unsigned short* Kbase = qkv + (size_t)(b * TT) * (3 * CC) + CC + h * DD;
  const unsigned short* Vbase = VT + (size_t)bh * DD * TT;

  // Q as B-operand frags, pre-scaled to log2 domain
  bfx8 qf[4];
  {
    const unsigned short* qp = qkv + (size_t)(b * TT + qrow) * (3 * CC) + h * DD;
    const float SC = 0.125f * 1.44269504088896340736f;
#pragma unroll
    for (int c = 0; c < 4; ++c) {
      bfx8 rw = *(const bfx8*)(qp + c * 16 + hi * 8);
#pragma unroll
      for (int j = 0; j < 8; ++j) qf[c][j] = (__bf16)((float)rw[j] * SC);
    }
  }

  f32x16 o0 = {}, o1 = {};
  float l_run = 0.f;     // per-half partial; cross-half combined once in epilogue

  // stage one 128-k step (two 64-wide sub-tiles): 512 threads -> 1 slot each per matrix/half
  auto stage = [&](int it, int bufi) {
    const int t64 = t0i + it * 2;
#pragma unroll
    for (int half = 0; half < 2; ++half) {
      const int k0 = (t64 + half) * 64;
      int row = tid >> 3;
      int q = (tid & 7) ^ (row & 7);
      gload_lds16(Kbase + (size_t)(k0 + row) * (3 * CC) + q * 8, &Ks[bufi][half][tid * 8]);
      gload_lds16(Vbase + (size_t)row * TT + k0 + q * 8, &Vs[bufi][half][tid * 8]);
    }
  };

  stage(0, 0);
  __syncthreads();

  int cur = 0;
  for (int it = 0; it < nIter; ++it) {
    if (it + 1 < nIter) stage(it + 1, cur ^ 1);   // prefetch overlaps both halves below

#pragma unroll
    for (int h2 = 0; h2 < 2; ++h2) {
      const int t = t0i + it * 2 + h2;
      const int k0 = t * 64;
      if (k0 <= qw + 31) {   // wave-uniform: skip fully-masked sub-tiles
        f32x16 sa[2];
        __builtin_amdgcn_s_setprio(1);
#pragma unroll
        for (int kh = 0; kh < 2; ++kh) {
          f32x16 acc = {};
          int row = kh * 32 + ql;
          int rx = row & 7;
#pragma unroll
          for (int c = 0; c < 4; ++c) {
            int quad = (c * 2 + hi) ^ rx;
            bfx8 kf = *(const bfx8*)(&Ks[cur][h2][row * 64 + quad * 8]);
            acc = __builtin_amdgcn_mfma_f32_32x32x16_bf16(kf, qf[c], acc, 0, 0, 0);
          }
          sa[kh] = acc;
        }
        __builtin_amdgcn_s_setprio(0);

        if (k0 + 63 > qw) {   // diagonal-region mask
#pragma unroll
          for (int kh = 0; kh < 2; ++kh)
#pragma unroll
            for (int r = 0; r < 16; ++r) {
              int kk = k0 + kh * 32 + (r & 3) + 8 * (r >> 2) + 4 * hi;
              if (kk > qrow) sa[kh][r] = -1e30f;
            }
        }

        // ---- p = exp2(s - MFIX) directly; 4 independent sum chains ----
        float rs0 = 0.f, rs1 = 0.f, rs2 = 0.f, rs3 = 0.f;
        unsigned pk[2][8];
#pragma unroll
        for (int kh = 0; kh < 2; ++kh)
#pragma unroll
          for (int i = 0; i < 8; ++i) {
            float p0 = __builtin_amdgcn_exp2f(sa[kh][2 * i] - MFIX);
            float p1 = __builtin_amdgcn_exp2f(sa[kh][2 * i + 1] - MFIX);
            float ps = p0 + p1;
            if ((i & 3) == 0) rs0 += ps;
            else if ((i & 3) == 1) rs1 += ps;
            else if ((i & 3) == 2) rs2 += ps;
            else rs3 += ps;
            pk[kh][i] = pack2bf(p0, p1);
          }
        l_run += (rs0 + rs1) + (rs2 + rs3);

        // ---- in-register P^T -> B-frags via permlane32_swap ----
        bfx8 pf[4];
#pragma unroll
        for (int kh = 0; kh < 2; ++kh)
#pragma unroll
          for (int c = 0; c < 2; ++c) {
            unsigned a0 = pk[kh][c * 4 + 0], a1 = pk[kh][c * 4 + 1];
            unsigned b0 = pk[kh][c * 4 + 2], b1 = pk[kh][c * 4 + 3];
            asm volatile("v_permlane32_swap_b32 %0, %1" : "+v"(a0), "+v"(b0));
            asm volatile("v_permlane32_swap_b32 %0, %1" : "+v"(a1), "+v"(b1));
            union { unsigned u[4]; bfx8 v; } cvt;
            cvt.u[0] = a0; cvt.u[1] = a1; cvt.u[2] = b0; cvt.u[3] = b1;
            pf[kh * 2 + c] = cvt.v;
          }

        __builtin_amdgcn_s_setprio(1);
#pragma unroll
        for (int kc = 0; kc < 4; ++kc) {
          {
            int row = ql;
            bfx8 vf = *(const bfx8*)(&Vs[cur][h2][row * 64 + (((kc * 2 + hi) ^ (row & 7)) * 8)]);
            o0 = __builtin_amdgcn_mfma_f32_32x32x16_bf16(vf, pf[kc], o0, 0, 0, 0);
          }
          {
            int row = 32 + ql;
            bfx8 vf = *(const bfx8*)(&Vs[cur][h2][row * 64 + (((kc * 2 + hi) ^ (row & 7)) * 8)]);
            o1 = __builtin_amdgcn_mfma_f32_32x32x16_bf16(vf, pf[kc], o1, 0, 0, 0);
          }
        }
        __builtin_amdgcn_s_setprio(0);
      }
    }

    __syncthreads();   // one barrier per 128-k step
    cur ^= 1;
  }

  // combine cross-half l once (sums commute over tiles)
  l_run += __shfl_xor(l_run, 32);

  if (nchunks == 1) {
    float inv = 1.0f / l_run;
    unsigned short* orow = aout + (size_t)(b * TT + qrow) * CC + h * DD;
#pragma unroll
    for (int dh = 0; dh < 2; ++dh) {
      const f32x16& oo = dh ? o1 : o0;
#pragma unroll
      for (int qd = 0; qd < 4; ++qd) {
        ushort4 v;
        v.x = f2b(oo[qd * 4 + 0] * inv);
        v.y = f2b(oo[qd * 4 + 1] * inv);
        v.z = f2b(oo[qd * 4 + 2] * inv);
        v.w = f2b(oo[qd * 4 + 3] * inv);
        *(ushort4*)(orow + dh * 32 + 8 * qd + 4 * hi) = v;
      }
    }
  } else {
    unsigned short* orow = opart + (size_t)sub * TBT * CC + (size_t)(b * TT + qrow) * CC + h * DD;
#pragma unroll
    for (int dh = 0; dh < 2; ++dh) {
      const f32x16& oo = dh ? o1 : o0;
#pragma unroll
      for (int qd = 0; qd < 4; ++qd) {
        ushort4 v;
        v.x = f2b(oo[qd * 4 + 0]);
        v.y = f2b(oo[qd * 4 + 1]);
        v.z = f2b(oo[qd * 4 + 2]);
        v.w = f2b(oo[qd * 4 + 3]);
        *(ushort4*)(orow + dh * 32 + 8 * qd + 4 * hi) = v;
      }
    }
    if (hi == 0) lbuf[((size_t)sub * (BB * HH) + bh) * TT + qrow] = l_run;
  }
}

// ---------------- attention combine: plain sum of partials (shared fixed m) --------------
// Grid covers ONLY the multi-chunk region t in [512, 2048) per batch.
__global__ __launch_bounds__(256) void k_attn_combine(const unsigned short* __restrict__ opart,
                                                      const float* __restrict__ lbuf,
                                                      unsigned short* __restrict__ aout) {
  int lin = (blockIdx.x * 256 + threadIdx.x) * 4;   // over BB x 1536 x CC elems
  int b = lin / (1536 * CC);
  int rem = lin - b * (1536 * CC);
  int t = 512 + rem / CC;
  int c = rem % CC;
  int idx = (b * TT + t) * CC + c;
  int bx8 = t >> 8;
  int cnt = (4 * bx8 + 11) >> 3;               // 2..4 in this region
  int h = c >> 6;
  int bh = b * HH + h;

  float lsum = 0.f;
#pragma unroll
  for (int s = 0; s < 4; ++s)
    if (s < cnt) lsum += lbuf[((size_t)s * (BB * HH) + bh) * TT + t];
  float linv = 1.0f / lsum;

  float a0 = 0.f, a1 = 0.f, a2 = 0.f, a3 = 0.f;
#pragma unroll
  for (int s = 0; s < 4; ++s)
    if (s < cnt) {
      ushort4 v = *(const ushort4*)(opart + (size_t)s * TBT * CC + idx);
      a0 += b2f(v.x);
      a1 += b2f(v.y);
      a2 += b2f(v.z);
      a3 += b2f(v.w);
    }
  ushort4 o;
  o.x = f2b(a0 * linv);
  o.y = f2b(a1 * linv);
  o.z = f2b(a2 * linv);
  o.w = f2b(a3 * linv);
  *(ushort4*)(aout + idx) = o;
}

// ---------------- LayerNorm+combine: v = sum of NP bf16 partials + resid + bias, then LN --
template<int OUTF32, int RESB16, int NP>
__global__ __launch_bounds__(256) void k_layernorm_c(const unsigned short* __restrict__ in0,
                                                     const unsigned short* __restrict__ in1,
                                                     const unsigned short* __restrict__ in2,
                                                     const unsigned short* __restrict__ in3,
                                                     const float* __restrict__ residf,
                                                     const unsigned short* __restrict__ residb,
                                                     const float* __restrict__ biasv,
                                                     const float* __restrict__ gw,
                                                     const float* __restrict__ bw,
                                                     float* __restrict__ outf,
                                                     unsigned short* __restrict__ outb) {
  __shared__ float red[8];
  const int row = blockIdx.x;
  const int tid = threadIdx.x;
  float v[3];
  float s = 0.f;
#pragma unroll
  for (int j = 0; j < 3; ++j) {
    int c = tid + j * 256;
    size_t idx = (size_t)row * CC + c;
    float rv = RESB16 ? b2f(residb[idx]) : residf[idx];
    float acc = b2f(in0[idx]) + b2f(in1[idx]);
    if (NP == 4) acc += b2f(in2[idx]) + b2f(in3[idx]);
    v[j] = acc + rv + biasv[c];
    s += v[j];
  }
#pragma unroll
  for (int off = 32; off; off >>= 1) s += __shfl_xor(s, off);
  if ((tid & 63) == 0) red[tid >> 6] = s;
  __syncthreads();
  s = red[0] + red[1] + red[2] + red[3];
  float mu = s * (1.0f / CC);
  float qs = 0.f;
#pragma unroll
  for (int j = 0; j < 3; ++j) { float d = v[j] - mu; qs += d * d; }
#pragma unroll
  for (int off = 32; off; off >>= 1) qs += __shfl_xor(qs, off);
  if ((tid & 63) == 0) red[4 + (tid >> 6)] = qs;
  __syncthreads();
  qs = red[4] + red[5] + red[6] + red[7];
  float rstd = rsqrtf(qs * (1.0f / CC) + 1e-5f);
#pragma unroll
  for (int j = 0; j < 3; ++j) {
    int c = tid + j * 256;
    float y = (v[j] - mu) * rstd * gw[c] + bw[c];
    if (OUTF32) outf[(size_t)row * CC + c] = y;
    else        outb[(size_t)row * CC + c] = f2b(y);
  }
}

extern "C" void kernel_launch(void* const* d_in, const int* in_sizes, int n_in,
                              void* d_out, int out_size, void* d_ws, size_t ws_size,
                              hipStream_t stream) {
  (void)in_sizes; (void)n_in; (void)out_size; (void)ws_size;
  const float* x    = (const float*)d_in[0];
  const float* Wqkv = (const float*)d_in[1];
  const float* bqkv = (const float*)d_in[2];
  const float* Wo   = (const float*)d_in[3];
  const float* bo   = (const float*)d_in[4];
  const float* ln1g = (const float*)d_in[5];
  const float* ln1b = (const float*)d_in[6];
  const float* Wf   = (const float*)d_in[7];
  const float* bf_  = (const float*)d_in[8];
  const float* Wp   = (const float*)d_in[9];
  const float* bp   = (const float*)d_in[10];
  const float* ln2g = (const float*)d_in[11];
  const float* ln2b = (const float*)d_in[12];

  char* ws = (char*)d_ws;
  size_t off = 0;
  auto alloc = [&](size_t bytes) {
    void* p = ws + off;
    off += (bytes + 255) & ~(size_t)255;
    return p;
  };
  unsigned short* xb    = (unsigned short*)alloc((size_t)TBT * CC * 2);
  unsigned short* WqkvT = (unsigned short*)alloc((size_t)3 * CC * CC * 2);
  unsigned short* WoT   = (unsigned short*)alloc((size_t)CC * CC * 2);
  unsigned short* WfT   = (unsigned short*)alloc((size_t)4 * CC * CC * 2);
  unsigned short* WpT   = (unsigned short*)alloc((size_t)4 * CC * CC * 2);
  unsigned short* qkvb  = (unsigned short*)alloc((size_t)TBT * 3 * CC * 2);
  unsigned short* VTb   = (unsigned short*)alloc((size_t)TBT * CC * 2);
  float*          hbuf  = (float*)alloc((size_t)TBT * CC * 4);
  unsigned short* hlnb  = (unsigned short*)alloc((size_t)TBT * CC * 2);
  unsigned short* gbuf  = (unsigned short*)alloc((size_t)TBT * 4 * CC * 2);

  const size_t S = (size_t)TBT * CC;

  // aliases (lifetime-disjoint):
  unsigned short* aout  = xb;                               // attn final out (xb dead after QKV GEMM)
  unsigned short* opart = gbuf;                             // attn O-partials, 4 x 6.3MB bf16
  float*          lvals = (float*)hbuf;                     // attn l sums (hbuf free here)
  unsigned short* woP0b = gbuf;                             // Wo split-K2 partials z=0,1 (opart dead)
  unsigned short* fpP01 = (unsigned short*)hbuf;            // FFN2 split-K4 partials z=0,1 (lvals dead)
  unsigned short* fpP23 = qkvb;                             // z=2,3 (qkvb dead after attention)

  // prep: x->bf16 + all 4 weight transposes (single launch)
  k_prep<<<9984, 256, 0, stream>>>(x, xb, Wqkv, WqkvT, Wo, WoT, Wf, WfT, Wp, WpT);

  // qkv = x @ Wqkv + bqkv -> bf16 [4096, 2304]; V columns transposed straight into VTb
  k_gemm_bt<0><<<dim3(3 * CC / 128, TBT / 128), 256, 0, stream>>>(
      xb, WqkvT, bqkv, qkvb, VTb, TBT, 3 * CC, CC);
  // attention pass 1 (8-wave blocks, 256 q-rows, KVBLK=128, XCD-grouped) -> aout + opart/l
  k_attn<<<480, 512, 0, stream>>>(qkvb, VTb, aout, opart, lvals);
  // combine multi-chunk rows (plain sum, t>=512 region only) -> aout bf16
  k_attn_combine<<<(BB * 1536 * CC) / 1024, 256, 0, stream>>>(opart, lvals, aout);
  // attn @ Wo (split-K=2) -> woP0b, woP0b+S bf16 partials
  k_gemm_bt<3><<<dim3(CC / 128, TBT / 128, 2), 256, 0, stream>>>(
      aout, WoT, nullptr, woP0b, nullptr, TBT, CC, CC);
  // LN1( woP0 + woP1 + x + bo ) -> hlnb (bf16)
  k_layernorm_c<0, 0, 2><<<TBT, 256, 0, stream>>>(woP0b, woP0b + S, nullptr, nullptr,
                                                  x, nullptr, bo, ln1g, ln1b, nullptr, hlnb);
  // g = gelu(hlnb @ Wf + bf) -> bf16 [4096, 3072]
  k_gemm_bt<1><<<dim3(4 * CC / 128, TBT / 128), 256, 0, stream>>>(
      hlnb, WfT, bf_, gbuf, nullptr, TBT, 4 * CC, CC);
  // g @ Wp (split-K=4) -> fpP01/fpP23 bf16 partials
  k_gemm_bt<3><<<dim3(CC / 128, TBT / 128, 4), 256, 0, stream>>>(
      gbuf, WpT, nullptr, fpP01, fpP23, TBT, CC, 4 * CC);
  // LN2( sum fpP + hlnb + bp ) -> d_out (f32)
  k_layernorm_c<1, 1, 4><<<TBT, 256, 0, stream>>>(fpP01, fpP01 + S, fpP23, fpP23 + S,
                                                  nullptr, hlnb, bp, ln2g, ln2b,
                                                  (float*)d_out, nullptr);
}

// Round 22
// 163.600 us; speedup vs baseline: 1.0409x; 1.0313x over previous
//
#include <hip/hip_runtime.h>

#define BB 2
#define TT 2048
#define CC 768
#define HH 12
#define DD 64
#define TBT (BB * TT)   // 4096 rows

typedef __bf16 bfx8 __attribute__((ext_vector_type(8)));
typedef float f32x4 __attribute__((ext_vector_type(4)));
typedef float f32x16 __attribute__((ext_vector_type(16)));

__device__ __forceinline__ unsigned short f2b(float f) {
  unsigned u = __float_as_uint(f);
  return (unsigned short)((u + 0x7FFFu + ((u >> 16) & 1u)) >> 16);
}
__device__ __forceinline__ float b2f(unsigned short u) {
  return __uint_as_float(((unsigned)u) << 16);
}

__device__ __forceinline__ unsigned pack2bf(float lo, float hi) {
  union { __bf16 h[2]; unsigned u; } x;
  x.h[0] = (__bf16)lo; x.h[1] = (__bf16)hi;
  return x.u;   // compiler emits v_cvt_pk_bf16_f32
}

__device__ __forceinline__ void gload_lds16(const void* g, void* l) {
  __builtin_amdgcn_global_load_lds((const __attribute__((address_space(1))) void*)g,
                                   (__attribute__((address_space(3))) void*)l, 16, 0, 0);
}

// fast exact-enough GELU (tanh form): |err| < 4e-4 vs erf form
__device__ __forceinline__ float gelu_fast(float v) {
  float t = v * v;
  float s = fmaf(0.10294663f, t, 2.3021582f);
  float e = __builtin_amdgcn_exp2f(-v * s);
  return v * __builtin_amdgcn_rcpf(1.0f + e);
}

// ---------------- unified prep: x->bf16 convert + all 4 weight transposes (1 launch) ------
__global__ __launch_bounds__(256) void k_prep(const float* __restrict__ x,
                                              unsigned short* __restrict__ xb,
                                              const float* __restrict__ Wqkv,
                                              unsigned short* __restrict__ WqkvT,
                                              const float* __restrict__ Wo,
                                              unsigned short* __restrict__ WoT,
                                              const float* __restrict__ Wf,
                                              unsigned short* __restrict__ WfT,
                                              const float* __restrict__ Wp,
                                              unsigned short* __restrict__ WpT) {
  __shared__ float tile[32][33];
  int bid = blockIdx.x;
  const int tid = threadIdx.x;
  if (bid < 3072) {
    int i = bid * 1024 + tid * 4;
    float4 v = *(const float4*)(x + i);
    ushort4 o;
    o.x = f2b(v.x); o.y = f2b(v.y); o.z = f2b(v.z); o.w = f2b(v.w);
    *(ushort4*)(xb + i) = o;
    return;
  }
  bid -= 3072;
  const float* W; unsigned short* WT; int K, N, bx, by;
  if (bid < 1728)              { W = Wqkv; WT = WqkvT; K = 768;  N = 2304; bx = bid % 72; by = bid / 72; }
  else if (bid < 1728 + 576)   { bid -= 1728; W = Wo; WT = WoT; K = 768;  N = 768;  bx = bid % 24; by = bid / 24; }
  else if (bid < 1728 + 576 + 2304) { bid -= 1728 + 576; W = Wf; WT = WfT; K = 768; N = 3072; bx = bid % 96; by = bid / 96; }
  else                         { bid -= 1728 + 576 + 2304; W = Wp; WT = WpT; K = 3072; N = 768; bx = bid % 24; by = bid / 24; }
  int n0 = bx * 32, k0 = by * 32;
  int j = tid & 31, i0 = tid >> 5;
  for (int i = i0; i < 32; i += 8) tile[i][j] = W[(size_t)(k0 + i) * N + n0 + j];
  __syncthreads();
  for (int i = i0; i < 32; i += 8) WT[(size_t)(n0 + i) * K + k0 + j] = f2b(tile[j][i]);
}

// ---------------- GEMM: C[M,N] = A[M,K] @ B[K,N],  Bt given as [N,K] ----------------
// 2-phase double-buffered staging: stage(k+1) issued BEFORE compute(k).
// MODE 0: out = bf16(acc + bias); V-column blocks (n0 >= 2C) write transposed into vt
// MODE 1: out = bf16(gelu_fast(acc + bias))
// MODE 3: split-K over blockIdx.z (2 halves): bf16 partial (no bias); z=0 -> outb, z=1 -> vt
template<int MODE>
__global__ __launch_bounds__(256) void k_gemm_bt(const unsigned short* __restrict__ A,
                                                 const unsigned short* __restrict__ Bt,
                                                 const float* __restrict__ bias,
                                                 unsigned short* __restrict__ outb,
                                                 unsigned short* __restrict__ vt,
                                                 int M, int N, int K) {
  __shared__ __align__(16) unsigned short SMEM[4][128 * 64];   // A[2] + B[2], 64KB
  const int tid = threadIdx.x;
  const int l = tid & 63, w = tid >> 6;
  const int wr = w >> 1, wc = w & 1;
  const int lr = l & 15, g = l >> 4;

  const int gx = gridDim.x, nwg = gx * gridDim.y;
  const int orig = blockIdx.x + gx * blockIdx.y;
  const int q8 = nwg >> 3;
  const int swz = (orig & 7) * q8 + (orig >> 3);
  const int m0 = (swz / gx) * 128, n0 = (swz % gx) * 128;

  int kbeg = 0, kend = K;
  if (MODE == 3) { int K2 = K >> 1; kbeg = blockIdx.z * K2; kend = kbeg + K2; }

  f32x4 acc[4][4] = {};

  auto stage = [&](int kt, int buf) {
#pragma unroll
    for (int i = 0; i < 4; ++i) {
      int s = tid + i * 256;           // 16B slot index, 0..1023
      int row = s >> 3;
      int q = (s & 7) ^ (row & 7);     // inverse-swizzled global source (linear LDS dest)
      gload_lds16(A + (size_t)(m0 + row) * K + kt + q * 8, &SMEM[buf][s * 8]);
      gload_lds16(Bt + (size_t)(n0 + row) * K + kt + q * 8, &SMEM[2 + buf][s * 8]);
    }
  };

  stage(kbeg, 0);
  __syncthreads();

  int cur = 0;
  for (int kt = kbeg; kt < kend; kt += 64) {
    if (kt + 64 < kend) stage(kt + 64, cur ^ 1);   // prefetch overlaps compute below
    const unsigned short* As = &SMEM[cur][0];
    const unsigned short* Bs = &SMEM[2 + cur][0];
#pragma unroll
    for (int kk = 0; kk < 2; ++kk) {
      bfx8 af[4], bfr[4];
#pragma unroll
      for (int m = 0; m < 4; ++m) {
        int row = wr * 64 + m * 16 + lr;
        int quad = (kk * 4 + g) ^ (row & 7);
        af[m] = *(const bfx8*)(&As[row * 64 + quad * 8]);
      }
#pragma unroll
      for (int n = 0; n < 4; ++n) {
        int row = wc * 64 + n * 16 + lr;
        int quad = (kk * 4 + g) ^ (row & 7);
        bfr[n] = *(const bfx8*)(&Bs[row * 64 + quad * 8]);
      }
#pragma unroll
      for (int m = 0; m < 4; ++m)
#pragma unroll
        for (int n = 0; n < 4; ++n)
          acc[m][n] = __builtin_amdgcn_mfma_f32_16x16x32_bf16(af[m], bfr[n], acc[m][n], 0, 0, 0);
    }
    __syncthreads();   // drains prefetch (vmcnt) + all waves done with buf[cur]
    cur ^= 1;
  }

  if (MODE == 0 && n0 >= 2 * CC) {
    // ---- fused V transpose: tile -> LDS (XOR-swizzled) -> coalesced vt write ----
    unsigned short* T = &SMEM[0][0];   // 32KB, all waves past final barrier
#pragma unroll
    for (int m = 0; m < 4; ++m)
#pragma unroll
      for (int n = 0; n < 4; ++n) {
        int tcol = wc * 64 + n * 16 + lr;
        float bv = bias[n0 + tcol];
#pragma unroll
        for (int r = 0; r < 4; ++r) {
          int trow = wr * 64 + m * 16 + g * 4 + r;
          T[tcol * 128 + (trow ^ ((tcol & 15) << 3))] = f2b(acc[m][n][r] + bv);
        }
      }
    __syncthreads();
    int tcol = tid >> 1, half = tid & 1;
    int gcol = n0 - 2 * CC + tcol;        // 0..767
    int hh = gcol >> 6, dd = gcol & 63;
    int bloc = m0 >> 11;
    int tb = m0 & 2047;
    unsigned short* dstrow = vt + ((size_t)(bloc * HH + hh) * DD + dd) * TT + tb;
#pragma unroll
    for (int c = 0; c < 8; ++c) {
      int tbase = half * 64 + c * 8;
      bfx8 val = *(const bfx8*)(&T[tcol * 128 + (tbase ^ ((tcol & 15) << 3))]);
      *(bfx8*)(dstrow + tbase) = val;
    }
    return;
  }

  unsigned short* dstb = (MODE == 3) ? (blockIdx.z ? vt : outb) : outb;
#pragma unroll
  for (int m = 0; m < 4; ++m) {
#pragma unroll
    for (int n = 0; n < 4; ++n) {
      int col = n0 + wc * 64 + n * 16 + lr;
      float bv = (MODE == 3) ? 0.f : bias[col];
#pragma unroll
      for (int r = 0; r < 4; ++r) {
        int row = m0 + wr * 64 + m * 16 + g * 4 + r;
        float v = acc[m][n][r] + bv;
        if (MODE == 1) v = gelu_fast(v);
        dstb[(size_t)row * N + col] = f2b(v);
      }
    }
  }
}

// ---------------- causal flash attention pass 1: 8 waves / 256 q-rows per block -----------
#define MFIX 8.0f
__device__ const unsigned char CBX8[20]  = {0,1, 2,2, 3,3, 4,4,4, 5,5,5, 6,6,6,6, 7,7,7,7};
__device__ const unsigned char CSUB8[20] = {0,0, 0,1, 0,1, 0,1,2, 0,1,2, 0,1,2,3, 0,1,2,3};
__global__ __launch_bounds__(512) void k_attn(const unsigned short* __restrict__ qkv,
                                              const unsigned short* __restrict__ VT,
                                              unsigned short* __restrict__ aout,
                                              unsigned short* __restrict__ opart,
                                              float* __restrict__ lbuf) {
  __shared__ __align__(16) unsigned short Ks[2][2][64 * 64];   // [dbuf][k-half]
  __shared__ __align__(16) unsigned short Vs[2][2][64 * 64];
  const int tid = threadIdx.x;
  const int l = tid & 63, w = tid >> 6;        // w in 0..7
  const int ql = l & 31, hi = l >> 5;

  // XCD-grouping decode: bijective [0,480) -> (cid in [0,20), bh in [0,24))
  const int id = blockIdx.x;
  const int c8 = id & 7;
  const int r8 = id >> 3;                      // 0..59
  const int cid = r8 % 20;
  const int bh = (r8 / 20) * 8 + c8;
  const int b = bh / HH, h = bh % HH;

  const int bx = CBX8[cid];
  const int sub = CSUB8[cid];
  const int nt = 4 * bx + 4;
  const int nchunks = (nt + 7) >> 3;
  const int t0i = sub * 8;
  const int tcount = min(8, nt - t0i);   // even, >= 4
  const int nIter = tcount >> 1;

  const int qw = bx * 256 + w * 32;    // this wave's 32 q-rows
  const int qrow = qw + ql;

  const unsigned short* Kbase = qkv + (size_t)(b * TT) * (3 * CC) + CC + h * DD;
  const unsigned short* Vbase = VT + (size_t)bh * DD * TT;

  // Q as B-operand frags, pre-scaled to log2 domain
  bfx8 qf[4];
  {
    const unsigned short* qp = qkv + (size_t)(b * TT + qrow) * (3 * CC) + h * DD;
    const float SC = 0.125f * 1.44269504088896340736f;
#pragma unroll
    for (int c = 0; c < 4; ++c) {
      bfx8 rw = *(const bfx8*)(qp + c * 16 + hi * 8);
#pragma unroll
      for (int j = 0; j < 8; ++j) qf[c][j] = (__bf16)((float)rw[j] * SC);
    }
  }

  f32x16 o0 = {}, o1 = {};
  float l_run = 0.f;     // per-half partial; cross-half combined once in epilogue

  // stage one 128-k step (two 64-wide sub-tiles): 512 threads -> 1 slot each per matrix/half
  auto stage = [&](int it, int bufi) {
    const int t64 = t0i + it * 2;
#pragma unroll
    for (int half = 0; half < 2; ++half) {
      const int k0 = (t64 + half) * 64;
      int row = tid >> 3;
      int q = (tid & 7) ^ (row & 7);
      gload_lds16(Kbase + (size_t)(k0 + row) * (3 * CC) + q * 8, &Ks[bufi][half][tid * 8]);
      gload_lds16(Vbase + (size_t)row * TT + k0 + q * 8, &Vs[bufi][half][tid * 8]);
    }
  };

  stage(0, 0);
  __syncthreads();

  int cur = 0;
  for (int it = 0; it < nIter; ++it) {
    if (it + 1 < nIter) stage(it + 1, cur ^ 1);   // prefetch overlaps both halves below

#pragma unroll
    for (int h2 = 0; h2 < 2; ++h2) {
      const int t = t0i + it * 2 + h2;
      const int k0 = t * 64;
      if (k0 <= qw + 31) {   // wave-uniform: skip fully-masked sub-tiles
        f32x16 sa[2];
        __builtin_amdgcn_s_setprio(1);
#pragma unroll
        for (int kh = 0; kh < 2; ++kh) {
          f32x16 acc = {};
          int row = kh * 32 + ql;
          int rx = row & 7;
#pragma unroll
          for (int c = 0; c < 4; ++c) {
            int quad = (c * 2 + hi) ^ rx;
            bfx8 kf = *(const bfx8*)(&Ks[cur][h2][row * 64 + quad * 8]);
            acc = __builtin_amdgcn_mfma_f32_32x32x16_bf16(kf, qf[c], acc, 0, 0, 0);
          }
          sa[kh] = acc;
        }
        __builtin_amdgcn_s_setprio(0);

        if (k0 + 63 > qw) {   // diagonal-region mask
#pragma unroll
          for (int kh = 0; kh < 2; ++kh)
#pragma unroll
            for (int r = 0; r < 16; ++r) {
              int kk = k0 + kh * 32 + (r & 3) + 8 * (r >> 2) + 4 * hi;
              if (kk > qrow) sa[kh][r] = -1e30f;
            }
        }

        // ---- p = exp2(s - MFIX) directly; 4 independent sum chains ----
        float rs0 = 0.f, rs1 = 0.f, rs2 = 0.f, rs3 = 0.f;
        unsigned pk[2][8];
#pragma unroll
        for (int kh = 0; kh < 2; ++kh)
#pragma unroll
          for (int i = 0; i < 8; ++i) {
            float p0 = __builtin_amdgcn_exp2f(sa[kh][2 * i] - MFIX);
            float p1 = __builtin_amdgcn_exp2f(sa[kh][2 * i + 1] - MFIX);
            float ps = p0 + p1;
            if ((i & 3) == 0) rs0 += ps;
            else if ((i & 3) == 1) rs1 += ps;
            else if ((i & 3) == 2) rs2 += ps;
            else rs3 += ps;
            pk[kh][i] = pack2bf(p0, p1);
          }
        l_run += (rs0 + rs1) + (rs2 + rs3);

        // ---- in-register P^T -> B-frags via permlane32_swap ----
        bfx8 pf[4];
#pragma unroll
        for (int kh = 0; kh < 2; ++kh)
#pragma unroll
          for (int c = 0; c < 2; ++c) {
            unsigned a0 = pk[kh][c * 4 + 0], a1 = pk[kh][c * 4 + 1];
            unsigned b0 = pk[kh][c * 4 + 2], b1 = pk[kh][c * 4 + 3];
            asm volatile("v_permlane32_swap_b32 %0, %1" : "+v"(a0), "+v"(b0));
            asm volatile("v_permlane32_swap_b32 %0, %1" : "+v"(a1), "+v"(b1));
            union { unsigned u[4]; bfx8 v; } cvt;
            cvt.u[0] = a0; cvt.u[1] = a1; cvt.u[2] = b0; cvt.u[3] = b1;
            pf[kh * 2 + c] = cvt.v;
          }

        __builtin_amdgcn_s_setprio(1);
#pragma unroll
        for (int kc = 0; kc < 4; ++kc) {
          {
            int row = ql;
            bfx8 vf = *(const bfx8*)(&Vs[cur][h2][row * 64 + (((kc * 2 + hi) ^ (row & 7)) * 8)]);
            o0 = __builtin_amdgcn_mfma_f32_32x32x16_bf16(vf, pf[kc], o0, 0, 0, 0);
          }
          {
            int row = 32 + ql;
            bfx8 vf = *(const bfx8*)(&Vs[cur][h2][row * 64 + (((kc * 2 + hi) ^ (row & 7)) * 8)]);
            o1 = __builtin_amdgcn_mfma_f32_32x32x16_bf16(vf, pf[kc], o1, 0, 0, 0);
          }
        }
        __builtin_amdgcn_s_setprio(0);
      }
    }

    __syncthreads();   // one barrier per 128-k step
    cur ^= 1;
  }

  // combine cross-half l once (sums commute over tiles)
  l_run += __shfl_xor(l_run, 32);

  if (nchunks == 1) {
    float inv = 1.0f / l_run;
    unsigned short* orow = aout + (size_t)(b * TT + qrow) * CC + h * DD;
#pragma unroll
    for (int dh = 0; dh < 2; ++dh) {
      const f32x16& oo = dh ? o1 : o0;
#pragma unroll
      for (int qd = 0; qd < 4; ++qd) {
        ushort4 v;
        v.x = f2b(oo[qd * 4 + 0] * inv);
        v.y = f2b(oo[qd * 4 + 1] * inv);
        v.z = f2b(oo[qd * 4 + 2] * inv);
        v.w = f2b(oo[qd * 4 + 3] * inv);
        *(ushort4*)(orow + dh * 32 + 8 * qd + 4 * hi) = v;
      }
    }
  } else {
    unsigned short* orow = opart + (size_t)sub * TBT * CC + (size_t)(b * TT + qrow) * CC + h * DD;
#pragma unroll
    for (int dh = 0; dh < 2; ++dh) {
      const f32x16& oo = dh ? o1 : o0;
#pragma unroll
      for (int qd = 0; qd < 4; ++qd) {
        ushort4 v;
        v.x = f2b(oo[qd * 4 + 0]);
        v.y = f2b(oo[qd * 4 + 1]);
        v.z = f2b(oo[qd * 4 + 2]);
        v.w = f2b(oo[qd * 4 + 3]);
        *(ushort4*)(orow + dh * 32 + 8 * qd + 4 * hi) = v;
      }
    }
    if (hi == 0) lbuf[((size_t)sub * (BB * HH) + bh) * TT + qrow] = l_run;
  }
}

// ---------------- attention combine: plain sum of partials (shared fixed m) --------------
// Grid covers ONLY the multi-chunk region t in [512, 2048) per batch.
__global__ __launch_bounds__(256) void k_attn_combine(const unsigned short* __restrict__ opart,
                                                      const float* __restrict__ lbuf,
                                                      unsigned short* __restrict__ aout) {
  int lin = (blockIdx.x * 256 + threadIdx.x) * 4;   // over BB x 1536 x CC elems
  int b = lin / (1536 * CC);
  int rem = lin - b * (1536 * CC);
  int t = 512 + rem / CC;
  int c = rem % CC;
  int idx = (b * TT + t) * CC + c;
  int bx8 = t >> 8;
  int cnt = (4 * bx8 + 11) >> 3;               // 2..4 in this region
  int h = c >> 6;
  int bh = b * HH + h;

  float lsum = 0.f;
#pragma unroll
  for (int s = 0; s < 4; ++s)
    if (s < cnt) lsum += lbuf[((size_t)s * (BB * HH) + bh) * TT + t];
  float linv = 1.0f / lsum;

  float a0 = 0.f, a1 = 0.f, a2 = 0.f, a3 = 0.f;
#pragma unroll
  for (int s = 0; s < 4; ++s)
    if (s < cnt) {
      ushort4 v = *(const ushort4*)(opart + (size_t)s * TBT * CC + idx);
      a0 += b2f(v.x);
      a1 += b2f(v.y);
      a2 += b2f(v.z);
      a3 += b2f(v.w);
    }
  ushort4 o;
  o.x = f2b(a0 * linv);
  o.y = f2b(a1 * linv);
  o.z = f2b(a2 * linv);
  o.w = f2b(a3 * linv);
  *(ushort4*)(aout + idx) = o;
}

// ---------------- LayerNorm+combine: v = bf16(in0)+bf16(in1)+resid+bias, then LN --------
template<int OUTF32, int RESB16>
__global__ __launch_bounds__(256) void k_layernorm_c(const unsigned short* __restrict__ in0,
                                                     const unsigned short* __restrict__ in1,
                                                     const float* __restrict__ residf,
                                                     const unsigned short* __restrict__ residb,
                                                     const float* __restrict__ biasv,
                                                     const float* __restrict__ gw,
                                                     const float* __restrict__ bw,
                                                     float* __restrict__ outf,
                                                     unsigned short* __restrict__ outb) {
  __shared__ float red[8];
  const int row = blockIdx.x;
  const int tid = threadIdx.x;
  float v[3];
  float s = 0.f;
#pragma unroll
  for (int j = 0; j < 3; ++j) {
    int c = tid + j * 256;
    size_t idx = (size_t)row * CC + c;
    float rv = RESB16 ? b2f(residb[idx]) : residf[idx];
    v[j] = b2f(in0[idx]) + b2f(in1[idx]) + rv + biasv[c];
    s += v[j];
  }
#pragma unroll
  for (int off = 32; off; off >>= 1) s += __shfl_xor(s, off);
  if ((tid & 63) == 0) red[tid >> 6] = s;
  __syncthreads();
  s = red[0] + red[1] + red[2] + red[3];
  float mu = s * (1.0f / CC);
  float qs = 0.f;
#pragma unroll
  for (int j = 0; j < 3; ++j) { float d = v[j] - mu; qs += d * d; }
#pragma unroll
  for (int off = 32; off; off >>= 1) qs += __shfl_xor(qs, off);
  if ((tid & 63) == 0) red[4 + (tid >> 6)] = qs;
  __syncthreads();
  qs = red[4] + red[5] + red[6] + red[7];
  float rstd = rsqrtf(qs * (1.0f / CC) + 1e-5f);
#pragma unroll
  for (int j = 0; j < 3; ++j) {
    int c = tid + j * 256;
    float y = (v[j] - mu) * rstd * gw[c] + bw[c];
    if (OUTF32) outf[(size_t)row * CC + c] = y;
    else        outb[(size_t)row * CC + c] = f2b(y);
  }
}

extern "C" void kernel_launch(void* const* d_in, const int* in_sizes, int n_in,
                              void* d_out, int out_size, void* d_ws, size_t ws_size,
                              hipStream_t stream) {
  (void)in_sizes; (void)n_in; (void)out_size; (void)ws_size;
  const float* x    = (const float*)d_in[0];
  const float* Wqkv = (const float*)d_in[1];
  const float* bqkv = (const float*)d_in[2];
  const float* Wo   = (const float*)d_in[3];
  const float* bo   = (const float*)d_in[4];
  const float* ln1g = (const float*)d_in[5];
  const float* ln1b = (const float*)d_in[6];
  const float* Wf   = (const float*)d_in[7];
  const float* bf_  = (const float*)d_in[8];
  const float* Wp   = (const float*)d_in[9];
  const float* bp   = (const float*)d_in[10];
  const float* ln2g = (const float*)d_in[11];
  const float* ln2b = (const float*)d_in[12];

  char* ws = (char*)d_ws;
  size_t off = 0;
  auto alloc = [&](size_t bytes) {
    void* p = ws + off;
    off += (bytes + 255) & ~(size_t)255;
    return p;
  };
  unsigned short* xb    = (unsigned short*)alloc((size_t)TBT * CC * 2);
  unsigned short* WqkvT = (unsigned short*)alloc((size_t)3 * CC * CC * 2);
  unsigned short* WoT   = (unsigned short*)alloc((size_t)CC * CC * 2);
  unsigned short* WfT   = (unsigned short*)alloc((size_t)4 * CC * CC * 2);
  unsigned short* WpT   = (unsigned short*)alloc((size_t)4 * CC * CC * 2);
  unsigned short* qkvb  = (unsigned short*)alloc((size_t)TBT * 3 * CC * 2);
  unsigned short* VTb   = (unsigned short*)alloc((size_t)TBT * CC * 2);
  float*          hbuf  = (float*)alloc((size_t)TBT * CC * 4);
  unsigned short* hlnb  = (unsigned short*)alloc((size_t)TBT * CC * 2);
  unsigned short* gbuf  = (unsigned short*)alloc((size_t)TBT * 4 * CC * 2);

  const size_t S = (size_t)TBT * CC;

  // aliases (lifetime-disjoint):
  unsigned short* aout  = xb;                               // attn final out (xb dead after QKV GEMM)
  unsigned short* opart = gbuf;                             // attn O-partials, 4 x 6.3MB bf16
  float*          lvals = (float*)hbuf;                     // attn l sums (hbuf free here)
  unsigned short* woP0b = gbuf;                             // Wo split-K bf16 partials (opart dead after combine)
  unsigned short* woP1b = gbuf + S;
  unsigned short* fpP0b = (unsigned short*)hbuf;            // FFN2 split-K bf16 partials (lvals dead)
  unsigned short* fpP1b = qkvb;                             // (qkvb dead after attention pass 1)

  // prep: x->bf16 + all 4 weight transposes (single launch)
  k_prep<<<9984, 256, 0, stream>>>(x, xb, Wqkv, WqkvT, Wo, WoT, Wf, WfT, Wp, WpT);

  // qkv = x @ Wqkv + bqkv -> bf16 [4096, 2304]; V columns transposed straight into VTb
  k_gemm_bt<0><<<dim3(3 * CC / 128, TBT / 128), 256, 0, stream>>>(
      xb, WqkvT, bqkv, qkvb, VTb, TBT, 3 * CC, CC);
  // attention pass 1 (8-wave blocks, 256 q-rows, KVBLK=128, XCD-grouped) -> aout + opart/l
  k_attn<<<480, 512, 0, stream>>>(qkvb, VTb, aout, opart, lvals);
  // combine multi-chunk rows (plain sum, t>=512 region only) -> aout bf16
  k_attn_combine<<<(BB * 1536 * CC) / 1024, 256, 0, stream>>>(opart, lvals, aout);
  // attn @ Wo (split-K=2) -> woP0b/woP1b bf16 partials
  k_gemm_bt<3><<<dim3(CC / 128, TBT / 128, 2), 256, 0, stream>>>(
      aout, WoT, nullptr, woP0b, woP1b, TBT, CC, CC);
  // LN1( woP0b+woP1b + x + bo ) -> hlnb (bf16)
  k_layernorm_c<0, 0><<<TBT, 256, 0, stream>>>(woP0b, woP1b, x, nullptr, bo,
                                               ln1g, ln1b, nullptr, hlnb);
  // g = gelu(hlnb @ Wf + bf) -> bf16 [4096, 3072]
  k_gemm_bt<1><<<dim3(4 * CC / 128, TBT / 128), 256, 0, stream>>>(
      hlnb, WfT, bf_, gbuf, nullptr, TBT, 4 * CC, CC);
  // g @ Wp (split-K=2) -> fpP0b/fpP1b bf16 partials
  k_gemm_bt<3><<<dim3(CC / 128, TBT / 128, 2), 256, 0, stream>>>(
      gbuf, WpT, nullptr, fpP0b, fpP1b, TBT, CC, 4 * CC);
  // LN2( fpP0b+fpP1b + hlnb + bp ) -> d_out (f32)
  k_layernorm_c<1, 1><<<TBT, 256, 0, stream>>>(fpP0b, fpP1b, nullptr, hlnb, bp,
                                               ln2g, ln2b, (float*)d_out, nullptr);
}